// Round 2
// baseline (289.719 us; speedup 1.0000x reference)
//
#include <hip/hip_runtime.h>

// Guided filter, R=1, EPS=1e-6, (8,3,1024,1024) fp32 — row-streaming separable.
//
// Block = 256 threads = 256 output columns; streams TH output rows.
// Per iteration (row r): load x,y row -> LDS; horizontal 3-sums (hx,hy,hxy,hxx)
// per thread (its A-column) kept in a 3-deep register ring (vertical sums are
// same-column => same-thread => registers, no LDS); A,b for row r-1 -> LDS row;
// horizontal 3-sums of A,b -> register ring; output row r-2.
//
// Edge semantics (replication pad, applied per box):
//  * columns: A at virtual col pa must equal A(clamp(pa)) -> per-thread index
//    jc = clamp(pa)-ob+2 into the halo-2 row buffer (clamp the CENTER, the
//    buffer itself stores x at clamped global cols so taps are then correct).
//  * rows: h at a singly-virtual row equals h(clamped row) automatically
//    (all 3 taps come from the same clamped x-row load). The only failures are
//    the doubly-virtual rows A(-1) (top blocks) and A(H) (bottom blocks):
//    fix by duplicating the hA/hB ring slot of the clamped row (see FIXUPs).

#define TH 32
#define NC 256
#define NIT (TH + 4)  // 36, multiple of 3

__global__ __launch_bounds__(256) void gf_kernel(const float* __restrict__ xg,
                                                 const float* __restrict__ yg,
                                                 float* __restrict__ outg,
                                                 int H, int W) {
  const int img = blockIdx.z;
  const size_t base = (size_t)img * H * W;
  const int ob = blockIdx.x * NC;   // first output col
  const int oy0 = blockIdx.y * TH;  // first output row
  const int t = threadIdx.x;        // 0..255

  __shared__ float rx[3][NC + 4];  // x row ring (3 rows needed: out reads r-2)
  __shared__ float ry[NC + 4];     // y current row
  __shared__ float rowA[NC + 2];   // A at cols [ob-1, ob+NC]
  __shared__ float rowB[NC + 2];

  // tile col t holds x(clamp(ob-2+t)); extra cols 256..259 loaded by t<4
  const int gc0 = min(max(ob - 2 + t, 0), W - 1);
  const int gcx = min(max(ob + 254 + t, 0), W - 1);  // used when t<4
  // A-col a=t -> global pa=ob-1+t; clamp CENTER, map to tile col
  const int jc = min(max(ob - 1 + t, 0), W - 1) - ob + 2;
  const int jc2 = min(max(ob + 255 + t, 0), W - 1) - ob + 2;  // dup col (t<2)
  const int oc = ob + t;

  const bool topfix = (oy0 == 0);
  const bool botfix = (oy0 == H - TH);

  float hx[3], hy[3], hxy[3], hxx[3];  // h-window, own A-column
  float kx[3], ky[3], kxy[3], kxx[3];  // dup A-column window (t<2)
  float hA[3], hB[3];
#pragma unroll
  for (int s = 0; s < 3; ++s) {
    hx[s] = hy[s] = hxy[s] = hxx[s] = 0.f;
    kx[s] = ky[s] = kxy[s] = kxx[s] = 0.f;
    hA[s] = hB[s] = 0.f;
  }

  const float inv9 = 1.0f / 9.0f;

#define BODY(S, I)                                                         \
  {                                                                        \
    const int i = (I);                                                     \
    const int r = oy0 - 2 + i;                                             \
    __syncthreads(); /* B1: protect rx[S], ry, rowA reuse */               \
    {                                                                      \
      const int rr = min(max(r, 0), H - 1);                                \
      const float* xr = xg + base + (size_t)rr * W;                        \
      const float* yr = yg + base + (size_t)rr * W;                        \
      rx[S][t] = xr[gc0];                                                  \
      ry[t] = yr[gc0];                                                     \
      if (t < 4) {                                                         \
        rx[S][256 + t] = xr[gcx];                                          \
        ry[256 + t] = yr[gcx];                                             \
      }                                                                    \
    }                                                                      \
    __syncthreads(); /* B2: loads -> h reads */                            \
    {                                                                      \
      float x0 = rx[S][jc - 1], x1 = rx[S][jc], x2 = rx[S][jc + 1];        \
      float y0 = ry[jc - 1], y1 = ry[jc], y2 = ry[jc + 1];                 \
      hx[S] = x0 + x1 + x2;                                                \
      hy[S] = y0 + y1 + y2;                                                \
      hxy[S] = x0 * y0 + x1 * y1 + x2 * y2;                                \
      hxx[S] = x0 * x0 + x1 * x1 + x2 * x2;                                \
      if (t < 2) {                                                         \
        float u0 = rx[S][jc2 - 1], u1 = rx[S][jc2], u2 = rx[S][jc2 + 1];   \
        float v0 = ry[jc2 - 1], v1 = ry[jc2], v2 = ry[jc2 + 1];            \
        kx[S] = u0 + u1 + u2;                                              \
        ky[S] = v0 + v1 + v2;                                              \
        kxy[S] = u0 * v0 + u1 * v1 + u2 * v2;                              \
        kxx[S] = u0 * u0 + u1 * u1 + u2 * u2;                              \
      }                                                                    \
    }                                                                      \
    if (i >= 2) { /* A,b at row r-1 */                                     \
      {                                                                    \
        float Sx = hx[0] + hx[1] + hx[2];                                  \
        float Sy = hy[0] + hy[1] + hy[2];                                  \
        float Sxy = hxy[0] + hxy[1] + hxy[2];                              \
        float Sxx = hxx[0] + hxx[1] + hxx[2];                              \
        float mx = Sx * inv9, my = Sy * inv9;                              \
        float cov = Sxy * inv9 - mx * my;                                  \
        float var = Sxx * inv9 - mx * mx;                                  \
        float d = var + 1e-6f;                                             \
        float inv = __builtin_amdgcn_rcpf(d);                              \
        inv = inv + inv * (1.0f - d * inv); /* 1 Newton step */            \
        float A = cov * inv;                                               \
        rowA[t] = A;                                                       \
        rowB[t] = my - A * mx;                                             \
      }                                                                    \
      if (t < 2) {                                                         \
        float Sx = kx[0] + kx[1] + kx[2];                                  \
        float Sy = ky[0] + ky[1] + ky[2];                                  \
        float Sxy = kxy[0] + kxy[1] + kxy[2];                              \
        float Sxx = kxx[0] + kxx[1] + kxx[2];                              \
        float mx = Sx * inv9, my = Sy * inv9;                              \
        float cov = Sxy * inv9 - mx * my;                                  \
        float var = Sxx * inv9 - mx * mx;                                  \
        float d = var + 1e-6f;                                             \
        float inv = __builtin_amdgcn_rcpf(d);                              \
        inv = inv + inv * (1.0f - d * inv);                                \
        float A = cov * inv;                                               \
        rowA[256 + t] = A;                                                 \
        rowB[256 + t] = my - A * mx;                                       \
      }                                                                    \
    }                                                                      \
    __syncthreads(); /* B3: rowA/rowB writes -> hA reads */                \
    if (i >= 2) {                                                          \
      float a0 = rowA[t], a1 = rowA[t + 1], a2 = rowA[t + 2];              \
      float b0 = rowB[t], b1 = rowB[t + 1], b2 = rowB[t + 2];              \
      hA[S] = a0 + a1 + a2;                                                \
      hB[S] = b0 + b1 + b2;                                                \
      /* FIXUP bottom: A(H) must be A(H-1): dup previous slot */           \
      if (botfix && i == NIT - 1) {                                        \
        hA[S] = hA[(S + 2) % 3];                                           \
        hB[S] = hB[(S + 2) % 3];                                           \
      }                                                                    \
      /* FIXUP top: overwrite bogus hA(-1) slot with hA(0) (i==3) */       \
      if (topfix && i == 3) {                                              \
        hA[(S + 2) % 3] = hA[S];                                           \
        hB[(S + 2) % 3] = hB[S];                                           \
      }                                                                    \
      if (i >= 4) { /* output row r-2 */                                   \
        float SA = hA[0] + hA[1] + hA[2];                                  \
        float SB = hB[0] + hB[1] + hB[2];                                  \
        float xv = rx[(S + 1) % 3][t + 2]; /* x(r-2, oc) */                \
        float res = (SA * xv + SB) * inv9;                                 \
        float tr = truncf(res);                                            \
        tr = fminf(fmaxf(tr, 0.0f), 255.0f);                               \
        outg[base + (size_t)(r - 2) * W + oc] = tr;                        \
      }                                                                    \
    }                                                                      \
  }

  for (int ii = 0; ii < NIT; ii += 3) {
    BODY(0, ii)
    BODY(1, ii + 1)
    BODY(2, ii + 2)
  }
#undef BODY
}

extern "C" void kernel_launch(void* const* d_in, const int* in_sizes, int n_in,
                              void* d_out, int out_size, void* d_ws, size_t ws_size,
                              hipStream_t stream) {
  const float* x = (const float*)d_in[0];
  const float* y = (const float*)d_in[1];
  float* out = (float*)d_out;
  const int H = 1024, W = 1024;
  const int imgs = in_sizes[0] / (H * W);  // 24
  dim3 block(256, 1, 1);
  dim3 grid(W / NC, H / TH, imgs);
  gf_kernel<<<grid, block, 0, stream>>>(x, y, out, H, W);
}

// Round 3
// 284.938 us; speedup vs baseline: 1.0168x; 1.0168x over previous
//
#include <hip/hip_runtime.h>

// Guided filter R=1, EPS=1e-6, (8,3,1024,1024) fp32.
// Barrier-free wave-streaming: zero LDS, zero __syncthreads.
// Each wave owns a 252-col x TH-row output chunk; 4 cols/lane
// (abs cols c0-2+4l+j, j=0..3; 64 lanes cover 256 cols = 252 outputs + halo 2).
// Cross-lane +-1 col halo via DPP WAVE_SHR1/WAVE_SHL1 (VALU pipe).
// Vertical 3-row windows are per-lane register rings (depth 3).
// Per-element clamped scalar loads give exact replication-pad taps.
// Edge semantics: doubly-virtual A cols (0, W-1) fixed by cndmask selecting
// own A (clamp-the-center); doubly-virtual A rows (-1, H) fixed by ring-slot
// duplication at top/bottom chunks.

#define NSTRIP 5
#define SOUT 252
#define TH 44
#define NIT (TH + 4)  // 48, multiple of 3

__device__ __forceinline__ float dpp_prev(float v) {  // lane n <- lane n-1
  return __int_as_float(__builtin_amdgcn_update_dpp(
      0, __float_as_int(v), 0x138, 0xF, 0xF, false));  // WAVE_SHR1
}
__device__ __forceinline__ float dpp_next(float v) {  // lane n <- lane n+1
  return __int_as_float(__builtin_amdgcn_update_dpp(
      0, __float_as_int(v), 0x130, 0xF, 0xF, false));  // WAVE_SHL1
}

__global__ __launch_bounds__(256) void gf_kernel(const float* __restrict__ xg,
                                                 const float* __restrict__ yg,
                                                 float* __restrict__ outg,
                                                 const int H, const int W,
                                                 const int nchunk) {
  const int tid = threadIdx.x;
  const int l = tid & 63;
  const int gw = (blockIdx.x << 2) + (tid >> 6);
  const int per_img = NSTRIP * nchunk;
  const int img = gw / per_img;
  const int rem = gw - img * per_img;
  const int chunk = rem / NSTRIP;
  const int strip = rem - chunk * NSTRIP;
  const int c0 = strip * SOUT;
  const int oy0 = min(chunk * TH, H - TH);  // last chunk overlaps (rewrites same values)
  const size_t base = (size_t)img * H * W;

  const int oc0 = c0 - 2 + 4 * l;  // abs col of this lane's j=0 slot
  const int cc0 = min(max(oc0, 0), W - 1);
  const int cc1 = min(max(oc0 + 1, 0), W - 1);
  const int cc2 = min(max(oc0 + 2, 0), W - 1);
  const int cc3 = min(max(oc0 + 3, 0), W - 1);
  const bool p0 = (l >= 1) && (oc0 < W);       // owns cols j0,j1
  const bool p1 = (l <= 62) && (oc0 + 2 < W);  // owns cols j2,j3
  const bool eL2 = (oc0 + 2 == 0);             // j2 is image col 0
  const bool eR1 = (oc0 + 1 == W - 1);         // j1 is image col W-1
  const bool tfixw = (oy0 == 0);
  const bool bfixw = (oy0 + TH == H);

  const float inv9 = 1.0f / 9.0f;

  float hx[3][4], hy[3][4], hxy[3][4], hxx[3][4];
  float sa[3][4], sb[3][4], xr3[3][4];
  float nx[4], ny[4];

  // preload row oy0-2 (clamped)
  {
    const int rn_ = min(max(oy0 - 2, 0), H - 1);
    const float* xr_ = xg + base + (size_t)rn_ * W;
    const float* yr_ = yg + base + (size_t)rn_ * W;
    nx[0] = xr_[cc0]; nx[1] = xr_[cc1]; nx[2] = xr_[cc2]; nx[3] = xr_[cc3];
    ny[0] = yr_[cc0]; ny[1] = yr_[cc1]; ny[2] = yr_[cc2]; ny[3] = yr_[cc3];
  }

#define BODY(S, PS, NS, I, DO_A, DO_OUT, DO_TFIX, DO_BFIX)                     \
  {                                                                            \
    const int i_ = (I);                                                        \
    const int rr_ = oy0 - 2 + i_;                                              \
    float cx[4], cy[4];                                                        \
    _Pragma("unroll") for (int j = 0; j < 4; ++j) {                            \
      cx[j] = nx[j];                                                           \
      cy[j] = ny[j];                                                           \
    }                                                                          \
    { /* depth-1 prefetch of next row (clamped; last iter re-reads H-1) */     \
      const int rn_ = min(max(rr_ + 1, 0), H - 1);                             \
      const float* xr_ = xg + base + (size_t)rn_ * W;                          \
      const float* yr_ = yg + base + (size_t)rn_ * W;                          \
      nx[0] = xr_[cc0]; nx[1] = xr_[cc1]; nx[2] = xr_[cc2]; nx[3] = xr_[cc3];  \
      ny[0] = yr_[cc0]; ny[1] = yr_[cc1]; ny[2] = yr_[cc2]; ny[3] = yr_[cc3];  \
    }                                                                          \
    const float xm_ = dpp_prev(cx[3]), xp_ = dpp_next(cx[0]);                  \
    const float ym_ = dpp_prev(cy[3]), yp_ = dpp_next(cy[0]);                  \
    hx[S][0] = xm_ + cx[0] + cx[1];                                            \
    hy[S][0] = ym_ + cy[0] + cy[1];                                            \
    hxy[S][0] = xm_ * ym_ + cx[0] * cy[0] + cx[1] * cy[1];                     \
    hxx[S][0] = xm_ * xm_ + cx[0] * cx[0] + cx[1] * cx[1];                     \
    hx[S][1] = cx[0] + cx[1] + cx[2];                                          \
    hy[S][1] = cy[0] + cy[1] + cy[2];                                          \
    hxy[S][1] = cx[0] * cy[0] + cx[1] * cy[1] + cx[2] * cy[2];                 \
    hxx[S][1] = cx[0] * cx[0] + cx[1] * cx[1] + cx[2] * cx[2];                 \
    hx[S][2] = cx[1] + cx[2] + cx[3];                                          \
    hy[S][2] = cy[1] + cy[2] + cy[3];                                          \
    hxy[S][2] = cx[1] * cy[1] + cx[2] * cy[2] + cx[3] * cy[3];                 \
    hxx[S][2] = cx[1] * cx[1] + cx[2] * cx[2] + cx[3] * cx[3];                 \
    hx[S][3] = cx[2] + cx[3] + xp_;                                            \
    hy[S][3] = cy[2] + cy[3] + yp_;                                            \
    hxy[S][3] = cx[2] * cy[2] + cx[3] * cy[3] + xp_ * yp_;                     \
    hxx[S][3] = cx[2] * cx[2] + cx[3] * cx[3] + xp_ * xp_;                     \
    _Pragma("unroll") for (int j = 0; j < 4; ++j) xr3[S][j] = cx[j];           \
    if (DO_A) { /* A,b at row rr_-1 */                                         \
      float A_[4], B_[4];                                                      \
      _Pragma("unroll") for (int j = 0; j < 4; ++j) {                          \
        const float Sx = hx[0][j] + hx[1][j] + hx[2][j];                       \
        const float Sy = hy[0][j] + hy[1][j] + hy[2][j];                       \
        const float Sxy = hxy[0][j] + hxy[1][j] + hxy[2][j];                   \
        const float Sxx = hxx[0][j] + hxx[1][j] + hxx[2][j];                   \
        const float mx = Sx * inv9, my = Sy * inv9;                            \
        const float cov = Sxy * inv9 - mx * my;                                \
        const float var = Sxx * inv9 - mx * mx;                                \
        const float d_ = var + 1e-6f;                                          \
        float v_ = __builtin_amdgcn_rcpf(d_);                                  \
        v_ = v_ + v_ * (1.0f - d_ * v_);                                       \
        A_[j] = cov * v_;                                                      \
        B_[j] = my - A_[j] * mx;                                               \
      }                                                                        \
      const float Am_ = dpp_prev(A_[3]), Ap_ = dpp_next(A_[0]);                \
      const float Bm_ = dpp_prev(B_[3]), Bp_ = dpp_next(B_[0]);                \
      sa[S][0] = Am_ + A_[0] + A_[1];                                          \
      sb[S][0] = Bm_ + B_[0] + B_[1];                                          \
      sa[S][1] = A_[0] + A_[1] + (eR1 ? A_[1] : A_[2]);                        \
      sb[S][1] = B_[0] + B_[1] + (eR1 ? B_[1] : B_[2]);                        \
      sa[S][2] = (eL2 ? A_[2] : A_[1]) + A_[2] + A_[3];                        \
      sb[S][2] = (eL2 ? B_[2] : B_[1]) + B_[2] + B_[3];                        \
      sa[S][3] = A_[2] + A_[3] + Ap_;                                          \
      sb[S][3] = B_[2] + B_[3] + Bp_;                                          \
      if (DO_TFIX && tfixw) { /* A(-1) := A(0) */                              \
        _Pragma("unroll") for (int j = 0; j < 4; ++j) {                        \
          sa[PS][j] = sa[S][j];                                                \
          sb[PS][j] = sb[S][j];                                                \
        }                                                                      \
      }                                                                        \
      if (DO_BFIX && bfixw) { /* A(H) := A(H-1) */                             \
        _Pragma("unroll") for (int j = 0; j < 4; ++j) {                        \
          sa[S][j] = sa[PS][j];                                                \
          sb[S][j] = sb[PS][j];                                                \
        }                                                                      \
      }                                                                        \
      if (DO_OUT) { /* output row rr_-2 */                                     \
        float* orow_ = outg + base + (size_t)(rr_ - 2) * W;                    \
        float o_[4];                                                           \
        _Pragma("unroll") for (int j = 0; j < 4; ++j) {                        \
          const float SA = sa[0][j] + sa[1][j] + sa[2][j];                     \
          const float SB = sb[0][j] + sb[1][j] + sb[2][j];                     \
          const float res = (SA * xr3[NS][j] + SB) * inv9;                     \
          o_[j] = fminf(fmaxf(truncf(res), 0.0f), 255.0f);                     \
        }                                                                      \
        if (p0) {                                                              \
          float2 v2; v2.x = o_[0]; v2.y = o_[1];                               \
          *(float2*)(orow_ + oc0) = v2;                                        \
        }                                                                      \
        if (p1) {                                                              \
          float2 v2; v2.x = o_[2]; v2.y = o_[3];                               \
          *(float2*)(orow_ + (oc0 + 2)) = v2;                                  \
        }                                                                      \
      }                                                                        \
    }                                                                          \
  }

  // prologue: bodies 0..5 (ring fill, top fixup, first outputs)
  BODY(0, 2, 1, 0, 0, 0, 0, 0)
  BODY(1, 0, 2, 1, 0, 0, 0, 0)
  BODY(2, 1, 0, 2, 1, 0, 0, 0)
  BODY(0, 2, 1, 3, 1, 0, 1, 0)
  BODY(1, 0, 2, 4, 1, 1, 0, 0)
  BODY(2, 1, 0, 5, 1, 1, 0, 0)
  // steady: bodies 6..44
  for (int ii = 6; ii <= NIT - 6; ii += 3) {
    BODY(0, 2, 1, ii, 1, 1, 0, 0)
    BODY(1, 0, 2, ii + 1, 1, 1, 0, 0)
    BODY(2, 1, 0, ii + 2, 1, 1, 0, 0)
  }
  // epilogue: bodies 45..47 (bottom fixup on last)
  BODY(0, 2, 1, NIT - 3, 1, 1, 0, 0)
  BODY(1, 0, 2, NIT - 2, 1, 1, 0, 0)
  BODY(2, 1, 0, NIT - 1, 1, 1, 0, 1)
#undef BODY
}

extern "C" void kernel_launch(void* const* d_in, const int* in_sizes, int n_in,
                              void* d_out, int out_size, void* d_ws, size_t ws_size,
                              hipStream_t stream) {
  const float* x = (const float*)d_in[0];
  const float* y = (const float*)d_in[1];
  float* out = (float*)d_out;
  const int H = 1024, W = 1024;
  const int imgs = in_sizes[0] / (H * W);      // 24
  const int nchunk = (H + TH - 1) / TH;        // 24
  const int waves = imgs * NSTRIP * nchunk;    // 2880
  dim3 block(256, 1, 1);
  dim3 grid(waves / 4, 1, 1);                  // 720 blocks, 4 waves each
  gf_kernel<<<grid, block, 0, stream>>>(x, y, out, H, W, nchunk);
}